// Round 1
// baseline (133.775 us; speedup 1.0000x reference)
//
#include <hip/hip_runtime.h>
#include <stdint.h>

#define B_  4096
#define F_  512
#define T_  2048
#define D_  4
#define M_  (T_ * D_)   // 8192 GEMM-M (trees*dims)
#define KC_ (F_ / 8)    // 64 16-byte k-chunks per row
#define TAU 0.2018004745467103f

typedef __attribute__((ext_vector_type(8)))  short bf16x8;
typedef __attribute__((ext_vector_type(16))) float f32x16;

static __device__ __forceinline__ unsigned short f2bf(float f) {
  union { float f; uint32_t u; } v; v.f = f;
  uint32_t r = v.u + 0x7fffu + ((v.u >> 16) & 1u);  // RNE
  return (unsigned short)(r >> 16);
}

// ---------------------------------------------------------------------------
// Prep (unchanged, verified): x -> xbF frag-major bf16, softmax(logits) -> wbF
// frag-major. Cell (kc, n) = 16B of 8 consecutive k for row n.
// ---------------------------------------------------------------------------
__global__ __launch_bounds__(256) void prep(
    const float* __restrict__ x, const float* __restrict__ logits,
    unsigned short* __restrict__ xbF, unsigned short* __restrict__ wbF) {
  if (blockIdx.x < 1024) {
    int w = blockIdx.x * 4 + (threadIdx.x >> 6);
    int l = threadIdx.x & 63;
    int n  = ((w & 511) << 3) + (l >> 3);
    int kc = ((w >> 9) << 3) + (l & 7);
    const float4* p = (const float4*)(x + (size_t)n * F_ + kc * 8);
    float4 a = p[0], b = p[1];
    bf16x8 o;
    o[0] = (short)f2bf(a.x); o[1] = (short)f2bf(a.y);
    o[2] = (short)f2bf(a.z); o[3] = (short)f2bf(a.w);
    o[4] = (short)f2bf(b.x); o[5] = (short)f2bf(b.y);
    o[6] = (short)f2bf(b.z); o[7] = (short)f2bf(b.w);
    *(bf16x8*)(xbF + ((size_t)kc * B_ + n) * 8) = o;
  } else {
    __shared__ uint32_t ls[4 * 257];
    int bj = blockIdx.x - 1024;
    int wv = threadIdx.x >> 6, l = threadIdx.x & 63;
    int m  = bj * 4 + wv;
    const float* src = logits + (size_t)m * F_ + l * 8;
    float4 v0 = *(const float4*)src;
    float4 v1 = *(const float4*)(src + 4);
    float mx = fmaxf(fmaxf(fmaxf(v0.x, v0.y), fmaxf(v0.z, v0.w)),
                     fmaxf(fmaxf(v1.x, v1.y), fmaxf(v1.z, v1.w)));
    #pragma unroll
    for (int s = 32; s >= 1; s >>= 1) mx = fmaxf(mx, __shfl_xor(mx, s, 64));
    float e[8];
    e[0] = __expf(v0.x - mx); e[1] = __expf(v0.y - mx);
    e[2] = __expf(v0.z - mx); e[3] = __expf(v0.w - mx);
    e[4] = __expf(v1.x - mx); e[5] = __expf(v1.y - mx);
    e[6] = __expf(v1.z - mx); e[7] = __expf(v1.w - mx);
    float sm = e[0] + e[1] + e[2] + e[3] + e[4] + e[5] + e[6] + e[7];
    #pragma unroll
    for (int s = 32; s >= 1; s >>= 1) sm += __shfl_xor(sm, s, 64);
    float inv = 1.0f / sm;
    union { bf16x8 v; uint32_t u[4]; } cv;
    #pragma unroll
    for (int i = 0; i < 8; i++) cv.v[i] = (short)f2bf(e[i] * inv);
    #pragma unroll
    for (int j = 0; j < 4; j++) ls[wv * 257 + l * 4 + j] = cv.u[j];
    __syncthreads();
    int kc = threadIdx.x >> 2, mm = threadIdx.x & 3;
    union { uint32_t u[4]; bf16x8 v; } rv;
    #pragma unroll
    for (int j = 0; j < 4; j++) rv.u[j] = ls[mm * 257 + kc * 4 + j];
    *(bf16x8*)(wbF + ((size_t)kc * M_ + bj * 4 + mm) * 8) = rv.v;
  }
}

// ---------------------------------------------------------------------------
// 256x256 8-phase MFMA GEMM (T3+T4+T5): BK=64, 8 waves (2x4), wave tile
// 128x64 of v_mfma_f32_32x32x16_bf16 (acc[4][2] f32x16 = 128 VGPR).
// LDS: 2 buffers x (A 32KB + B 32KB) = 128KB -> 1 block/CU, 2 waves/SIMD.
// Frag-major [kc][256 row] 16B cells: conflict-free ds_read_b128 AND linear
// 1KB chunks for global_load_lds (no swizzle needed, rule #21 satisfied).
//
// Per tile t: 4 phases = 4 C-quadrants (m0n0, m0n1, m1n1, m1n0); operand
// halves a0/a1/b0/b1 live in regs across phases. Each phase stages ONE 16KB
// half-tile whose LDS region was last ds_read in the PREVIOUS phase
// (barrier-pair separated):
//   q0: read A{0-63,128-191}+B{q0 rows}, stage B[128:256) of t+1 (other buf)
//   q1: read B{q1 rows},                 stage A{0-63,128-191} of t+2
//   q2: read A{64-127,192-255},          stage B[0:128)        of t+2
//   q3: (reg reuse only),                stage A{64-127,192-255} of t+2
// Single counted s_waitcnt vmcnt(6) at q3 (3 half-tiles = 6 loads stay in
// flight across barriers; tail drains with vmcnt(0) at t=6). Raw s_barrier
// (NO implicit vmcnt(0) drain - that drain was the 2-barrier structure's
// ~20% stall). setprio(1) brackets each MFMA cluster (T5).
// ---------------------------------------------------------------------------
#define SBAR()  do { __builtin_amdgcn_sched_barrier(0); \
                     __builtin_amdgcn_s_barrier(); \
                     __builtin_amdgcn_sched_barrier(0); } while (0)
#define LGKM0() do { asm volatile("s_waitcnt lgkmcnt(0)" ::: "memory"); \
                     __builtin_amdgcn_sched_barrier(0); } while (0)
#define VMCNT(n) do { asm volatile("s_waitcnt vmcnt(" #n ")" ::: "memory"); \
                      __builtin_amdgcn_sched_barrier(0); } while (0)

__global__ __launch_bounds__(512, 2) void odst_mfma(
    const unsigned short* __restrict__ wbF,  // frag-major [KC][M] 16B cells
    const unsigned short* __restrict__ xbF,  // frag-major [KC][B] 16B cells
    const float* __restrict__ thr,           // [T][4]
    const float* __restrict__ leaf,          // [T][16]
    float* __restrict__ out) {               // [B][T]
  __shared__ __align__(16) char smem[131072];

  const int tid  = threadIdx.x;
  const int lane = tid & 63, wid = tid >> 6;   // 8 waves
  const int wm = wid >> 2, wn = wid & 3;       // 2 (m) x 4 (n)
  const int col = lane & 31, hi = lane >> 5;
  const int m0 = blockIdx.x * 256;             // m fast -> share B strip (L2)
  const int n0 = blockIdx.y * 256;

  // Stage sources: wave `wid` owns kc slot `wid` of each tile; per phase each
  // thread issues 2 global_load_lds (1KB wave-chunks, LDS dest wave-uniform).
  const unsigned short* gA = wbF + ((size_t)wid * M_ + m0 + lane) * 8;
  const unsigned short* gB = xbF + ((size_t)wid * B_ + n0 + lane) * 8;

  auto stageA = [&](int t, int h2) {           // A rows {h2*64..+64, +128}
    char* base = smem + (t & 1) * 65536;
    #pragma unroll
    for (int j = 0; j < 2; ++j) {
      int rb = j * 128 + h2 * 64;
      __builtin_amdgcn_global_load_lds(
          (const __attribute__((address_space(1))) uint32_t*)(
              gA + ((size_t)t * 8 * M_ + rb) * 8),
          (__attribute__((address_space(3))) uint32_t*)(
              base + (wid * 256 + rb) * 16),
          16, 0, 0);
    }
  };
  auto stageB = [&](int t, int h2) {           // B rows [h2*128, h2*128+128)
    char* base = smem + (t & 1) * 65536 + 32768;
    #pragma unroll
    for (int j = 0; j < 2; ++j) {
      int rb = j * 64 + h2 * 128;
      __builtin_amdgcn_global_load_lds(
          (const __attribute__((address_space(1))) uint32_t*)(
              gB + ((size_t)t * 8 * B_ + rb) * 8),
          (__attribute__((address_space(3))) uint32_t*)(
              base + (wid * 256 + rb) * 16),
          16, 0, 0);
    }
  };

  bf16x8 a0[2][4], a1[2][4], b0[4], b1[4];
  f32x16 acc[4][2] = {};

  auto ldaf = [&](bf16x8 (&a)[2][4], int t, int mh) {
    const char* base = smem + (t & 1) * 65536;
    #pragma unroll
    for (int ks = 0; ks < 4; ++ks)
      #pragma unroll
      for (int mf = 0; mf < 2; ++mf)
        a[mf][ks] = *(const bf16x8*)(base +
            ((2 * ks + hi) * 256 + wm * 128 + mh * 64 + mf * 32 + col) * 16);
  };
  auto ldbf = [&](bf16x8 (&b)[4], int t, int nh) {
    const char* base = smem + (t & 1) * 65536 + 32768;
    #pragma unroll
    for (int ks = 0; ks < 4; ++ks)
      b[ks] = *(const bf16x8*)(base +
          ((2 * ks + hi) * 256 + wn * 64 + nh * 32 + col) * 16);
  };
  auto mmaq = [&](bf16x8 (&a)[2][4], bf16x8 (&b)[4], int mh, int nh) {
    __builtin_amdgcn_s_setprio(1);
    #pragma unroll
    for (int ks = 0; ks < 4; ++ks)
      #pragma unroll
      for (int mf = 0; mf < 2; ++mf)
        acc[2 * mh + mf][nh] = __builtin_amdgcn_mfma_f32_32x32x16_bf16(
            a[mf][ks], b[ks], acc[2 * mh + mf][nh], 0, 0, 0);
    __builtin_amdgcn_s_setprio(0);
  };

  // ---- prologue: tile 0 full + tile 1 {A0,B0,A1}; B1(1) staged at t0/q0 ----
  stageA(0, 0); stageB(0, 0); stageA(0, 1); stageB(0, 1);
  stageA(1, 0); stageB(1, 0); stageA(1, 1);
  VMCNT(6);                                  // tile 0's 8 loads landed
  SBAR();

  #pragma unroll 2
  for (int t = 0; t < 8; ++t) {              // K = 8 tiles x BK=64
    // -- phase 0: quadrant (m-half 0, n-half 0) --
    ldaf(a0, t, 0);
    ldbf(b0, t, 0);
    if (t < 7) stageB(t + 1, 1);             // other buffer
    SBAR(); LGKM0();
    mmaq(a0, b0, 0, 0);
    SBAR();
    // -- phase 1: (m0, n1) --
    ldbf(b1, t, 1);
    if (t < 6) stageA(t + 2, 0);             // overwrites q0-read A region
    SBAR(); LGKM0();
    mmaq(a0, b1, 0, 1);
    SBAR();
    // -- phase 2: (m1, n1) --
    ldaf(a1, t, 1);
    if (t < 6) stageB(t + 2, 0);             // overwrites q0/q1-read B region
    SBAR(); LGKM0();
    mmaq(a1, b1, 1, 1);
    SBAR();
    // -- phase 3: (m1, n0) -- (a1, b0 already in regs; no ds_read)
    if (t < 6) { stageA(t + 2, 1); VMCNT(6); }   // 3 half-tiles stay in flight
    else if (t == 6) { VMCNT(0); }               // tail drain for tile 7
    SBAR();
    mmaq(a1, b0, 1, 0);
    SBAR();
  }

  __syncthreads();  // full drain; LDS now reusable for epilogue staging

  // ---- fused epilogue: C-layout n=col, d=reg&3, tree_local=wm*32+mf*8+2g+hi
  float* eb = (float*)smem;                  // [256 batch][68] (16B-aligned)
  const float inv_tau = 1.0f / TAU;
  const int t0 = m0 >> 2;                    // 64 trees per block
  #pragma unroll
  for (int mf = 0; mf < 4; ++mf) {
    #pragma unroll
    for (int g = 0; g < 4; ++g) {
      int tl = wm * 32 + mf * 8 + 2 * g + hi;
      int tg = t0 + tl;
      float4 th  = *(const float4*)(thr + tg * 4);
      float4 lf0 = *(const float4*)(leaf + tg * 16);
      float4 lf1 = *(const float4*)(leaf + tg * 16 + 4);
      float4 lf2 = *(const float4*)(leaf + tg * 16 + 8);
      float4 lf3 = *(const float4*)(leaf + tg * 16 + 12);
      float c2x = th.x * inv_tau, c2y = th.y * inv_tau,
            c2z = th.z * inv_tau, c2w = th.w * inv_tau;
      #pragma unroll
      for (int nf = 0; nf < 2; ++nf) {
        float p0 = __builtin_amdgcn_rcpf(1.0f + __expf(fmaf(acc[mf][nf][g * 4 + 0], -inv_tau, c2x)));
        float p1 = __builtin_amdgcn_rcpf(1.0f + __expf(fmaf(acc[mf][nf][g * 4 + 1], -inv_tau, c2y)));
        float p2 = __builtin_amdgcn_rcpf(1.0f + __expf(fmaf(acc[mf][nf][g * 4 + 2], -inv_tau, c2z)));
        float p3 = __builtin_amdgcn_rcpf(1.0f + __expf(fmaf(acc[mf][nf][g * 4 + 3], -inv_tau, c2w)));
        float q0 = 1.0f - p0, q1 = 1.0f - p1, q2 = 1.0f - p2, q3 = 1.0f - p3;
        float A0 = lf0.x * q0 + lf0.y * p0;
        float A1 = lf0.z * q0 + lf0.w * p0;
        float A2 = lf1.x * q0 + lf1.y * p0;
        float A3 = lf1.z * q0 + lf1.w * p0;
        float A4 = lf2.x * q0 + lf2.y * p0;
        float A5 = lf2.z * q0 + lf2.w * p0;
        float A6 = lf3.x * q0 + lf3.y * p0;
        float A7 = lf3.z * q0 + lf3.w * p0;
        float B0 = A0 * q1 + A1 * p1;
        float B1 = A2 * q1 + A3 * p1;
        float B2 = A4 * q1 + A5 * p1;
        float B3 = A6 * q1 + A7 * p1;
        float C0 = B0 * q2 + B1 * p2;
        float C1 = B2 * q2 + B3 * p2;
        float o  = C0 * q3 + C1 * p3;
        int bl = wn * 64 + nf * 32 + col;    // batch within block
        eb[bl * 68 + tl] = o;                // stride 68: 16B-aligned rows
      }
    }
  }
  __syncthreads();

  // coalesced store: 256 batch rows x 64 trees, float4 per thread-slot
  #pragma unroll
  for (int pass = 0; pass < 8; ++pass) {
    int row = pass * 32 + (tid >> 4);
    int s   = tid & 15;
    float4 v = *(const float4*)(eb + row * 68 + s * 4);
    *(float4*)(out + (size_t)(n0 + row) * T_ + t0 + s * 4) = v;
  }
}

extern "C" void kernel_launch(void* const* d_in, const int* in_sizes, int n_in,
                              void* d_out, int out_size, void* d_ws, size_t ws_size,
                              hipStream_t stream) {
  const float* x    = (const float*)d_in[0];  // (B, F)
  const float* fl   = (const float*)d_in[1];  // (T, D, F)
  const float* thr  = (const float*)d_in[2];  // (T, D)
  const float* leaf = (const float*)d_in[3];  // (T, 16)
  float* out = (float*)d_out;                 // (B, T)

  unsigned short* wbF = (unsigned short*)d_ws;                                  // 8 MB
  unsigned short* xbF = (unsigned short*)((char*)d_ws + (size_t)KC_ * M_ * 16); // 4 MB

  prep<<<dim3(1024 + M_ / 4), dim3(256), 0, stream>>>(x, fl, xbF, wbF);
  odst_mfma<<<dim3(M_ / 256, B_ / 256), dim3(512), 0, stream>>>(wbF, xbF, thr, leaf, out);
}

// Round 2
// 127.359 us; speedup vs baseline: 1.0504x; 1.0504x over previous
//
#include <hip/hip_runtime.h>
#include <stdint.h>

#define B_  4096
#define F_  512
#define T_  2048
#define D_  4
#define M_  (T_ * D_)   // 8192 GEMM-M (trees*dims)
#define KC_ (F_ / 8)    // 64 16-byte k-chunks per row
#define TAU 0.2018004745467103f

typedef __attribute__((ext_vector_type(8)))  short bf16x8;
typedef __attribute__((ext_vector_type(16))) float f32x16;

static __device__ __forceinline__ unsigned short f2bf(float f) {
  union { float f; uint32_t u; } v; v.f = f;
  uint32_t r = v.u + 0x7fffu + ((v.u >> 16) & 1u);  // RNE
  return (unsigned short)(r >> 16);
}

// ---------------------------------------------------------------------------
// Prep (unchanged, verified): x -> xbF frag-major bf16, softmax(logits) -> wbF
// frag-major. Cell (kc, n) = 16B of 8 consecutive k for row n.
// ---------------------------------------------------------------------------
__global__ __launch_bounds__(256) void prep(
    const float* __restrict__ x, const float* __restrict__ logits,
    unsigned short* __restrict__ xbF, unsigned short* __restrict__ wbF) {
  if (blockIdx.x < 1024) {
    int w = blockIdx.x * 4 + (threadIdx.x >> 6);
    int l = threadIdx.x & 63;
    int n  = ((w & 511) << 3) + (l >> 3);
    int kc = ((w >> 9) << 3) + (l & 7);
    const float4* p = (const float4*)(x + (size_t)n * F_ + kc * 8);
    float4 a = p[0], b = p[1];
    bf16x8 o;
    o[0] = (short)f2bf(a.x); o[1] = (short)f2bf(a.y);
    o[2] = (short)f2bf(a.z); o[3] = (short)f2bf(a.w);
    o[4] = (short)f2bf(b.x); o[5] = (short)f2bf(b.y);
    o[6] = (short)f2bf(b.z); o[7] = (short)f2bf(b.w);
    *(bf16x8*)(xbF + ((size_t)kc * B_ + n) * 8) = o;
  } else {
    __shared__ uint32_t ls[4 * 257];
    int bj = blockIdx.x - 1024;
    int wv = threadIdx.x >> 6, l = threadIdx.x & 63;
    int m  = bj * 4 + wv;
    const float* src = logits + (size_t)m * F_ + l * 8;
    float4 v0 = *(const float4*)src;
    float4 v1 = *(const float4*)(src + 4);
    float mx = fmaxf(fmaxf(fmaxf(v0.x, v0.y), fmaxf(v0.z, v0.w)),
                     fmaxf(fmaxf(v1.x, v1.y), fmaxf(v1.z, v1.w)));
    #pragma unroll
    for (int s = 32; s >= 1; s >>= 1) mx = fmaxf(mx, __shfl_xor(mx, s, 64));
    float e[8];
    e[0] = __expf(v0.x - mx); e[1] = __expf(v0.y - mx);
    e[2] = __expf(v0.z - mx); e[3] = __expf(v0.w - mx);
    e[4] = __expf(v1.x - mx); e[5] = __expf(v1.y - mx);
    e[6] = __expf(v1.z - mx); e[7] = __expf(v1.w - mx);
    float sm = e[0] + e[1] + e[2] + e[3] + e[4] + e[5] + e[6] + e[7];
    #pragma unroll
    for (int s = 32; s >= 1; s >>= 1) sm += __shfl_xor(sm, s, 64);
    float inv = 1.0f / sm;
    union { bf16x8 v; uint32_t u[4]; } cv;
    #pragma unroll
    for (int i = 0; i < 8; i++) cv.v[i] = (short)f2bf(e[i] * inv);
    #pragma unroll
    for (int j = 0; j < 4; j++) ls[wv * 257 + l * 4 + j] = cv.u[j];
    __syncthreads();
    int kc = threadIdx.x >> 2, mm = threadIdx.x & 3;
    union { uint32_t u[4]; bf16x8 v; } rv;
    #pragma unroll
    for (int j = 0; j < 4; j++) rv.u[j] = ls[mm * 257 + kc * 4 + j];
    *(bf16x8*)(wbF + ((size_t)kc * M_ + bj * 4 + mm) * 8) = rv.v;
  }
}

// ---------------------------------------------------------------------------
// 256x128 tile, 4 waves (2m x 2n), wave tile 128x64, BK=32 double-buffered.
// LDS = 2 x (A 16KB + B 8KB) = 48KB -> 2 blocks/CU; regs ~100 VGPR + 128 AGPR
// = 2 waves/SIMD -> the two CO-RESIDENT BLOCKS cover each other's barrier
// stalls (the mechanism that made the 51us kernel work), while the counted
// vmcnt (never 0 in steady state) removes the full-drain stall.
// Grid 32x32 = 1024 blocks = exactly 2/CU -> ONE dispatch round, no tail.
//
// Per K-tile t (buf = t&1), 2 phases:
//  q0: stage A(t+1) rows{64-127,192-255} (pending buf; last read t-1 q1);
//      ds_read a_lo (A rows {0-63,128-191}, 4xb128) + b (all B, 4xb128);
//      SBAR; lgkm0; 8 MFMA (m-frags 0,1); SBAR.
//  q1: stage A(t+2) rows{0-63,128-191} + B(t+2) all (live buf; regions read
//      in q0, disjoint from q1's own reads); ds_read a_hi (rows {64-127,
//      192-255}); VMCNT(4) -> all of tile t+1 resident (only t q1's 4 stages
//      may remain in flight); SBAR; lgkm0; 8 MFMA (m-frags 2,3); SBAR.
// Tail: t=14 q1 VMCNT(0); t=15 pure compute.
// ---------------------------------------------------------------------------
#define SBAR()  do { __builtin_amdgcn_sched_barrier(0); \
                     __builtin_amdgcn_s_barrier(); \
                     __builtin_amdgcn_sched_barrier(0); } while (0)
#define LGKM0() do { asm volatile("s_waitcnt lgkmcnt(0)" ::: "memory"); \
                     __builtin_amdgcn_sched_barrier(0); } while (0)
#define VMCNT(n) do { asm volatile("s_waitcnt vmcnt(" #n ")" ::: "memory"); \
                      __builtin_amdgcn_sched_barrier(0); } while (0)

__global__ __launch_bounds__(256, 2) void odst_mfma(
    const unsigned short* __restrict__ wbF,  // frag-major [KC][M] 16B cells
    const unsigned short* __restrict__ xbF,  // frag-major [KC][B] 16B cells
    const float* __restrict__ thr,           // [T][4]
    const float* __restrict__ leaf,          // [T][16]
    float* __restrict__ out) {               // [B][T]
  __shared__ __align__(16) char smem[49152];

  const int tid  = threadIdx.x;
  const int lane = tid & 63, wid = tid >> 6;   // 4 waves
  const int wm = wid >> 1, wn = wid & 1;       // 2 (m) x 2 (n)
  const int col = lane & 31, hi = lane >> 5;
  const int m0 = blockIdx.x * 256;
  const int n0 = blockIdx.y * 128;

  // wave `wid` stages kc slot `wid` of each tile (4 kc slots per BK=32 tile)
  const unsigned short* gA = wbF + ((size_t)wid * M_ + m0 + lane) * 8;
  const unsigned short* gB = xbF + ((size_t)wid * B_ + n0 + lane) * 8;

  auto stA = [&](int t, int j) {               // A rows [j*64, j*64+64)
    char* base = smem + (t & 1) * 24576;
    __builtin_amdgcn_global_load_lds(
        (const __attribute__((address_space(1))) uint32_t*)(
            gA + ((size_t)t * 4 * M_ + j * 64) * 8),
        (__attribute__((address_space(3))) uint32_t*)(
            base + (wid * 256 + j * 64) * 16),
        16, 0, 0);
  };
  auto stB = [&](int t, int j) {               // B rows [j*64, j*64+64)
    char* base = smem + (t & 1) * 24576 + 16384;
    __builtin_amdgcn_global_load_lds(
        (const __attribute__((address_space(1))) uint32_t*)(
            gB + ((size_t)t * 4 * B_ + j * 64) * 8),
        (__attribute__((address_space(3))) uint32_t*)(
            base + (wid * 128 + j * 64) * 16),
        16, 0, 0);
  };

  bf16x8 alo[2][2], ahi[2][2], b[2][2];
  f32x16 acc[4][2] = {};

  auto ldA = [&](bf16x8 (&a)[2][2], int t, int mh) {  // m-frags mh*2+{0,1}
    const char* base = smem + (t & 1) * 24576;
    #pragma unroll
    for (int ks = 0; ks < 2; ++ks)
      #pragma unroll
      for (int mf = 0; mf < 2; ++mf)
        a[mf][ks] = *(const bf16x8*)(base +
            ((2 * ks + hi) * 256 + wm * 128 + (mh * 2 + mf) * 32 + col) * 16);
  };
  auto ldB = [&](int t) {
    const char* base = smem + (t & 1) * 24576 + 16384;
    #pragma unroll
    for (int ks = 0; ks < 2; ++ks)
      #pragma unroll
      for (int nf = 0; nf < 2; ++nf)
        b[nf][ks] = *(const bf16x8*)(base +
            ((2 * ks + hi) * 128 + wn * 64 + nf * 32 + col) * 16);
  };
  auto mmah = [&](bf16x8 (&a)[2][2], int mh) {
    __builtin_amdgcn_s_setprio(1);
    #pragma unroll
    for (int ks = 0; ks < 2; ++ks)
      #pragma unroll
      for (int mf = 0; mf < 2; ++mf)
        #pragma unroll
        for (int nf = 0; nf < 2; ++nf)
          acc[mh * 2 + mf][nf] = __builtin_amdgcn_mfma_f32_32x32x16_bf16(
              a[mf][ks], b[nf][ks], acc[mh * 2 + mf][nf], 0, 0, 0);
    __builtin_amdgcn_s_setprio(0);
  };

  // ---- prologue: tile 0 full (6) + tile 1 partial {A j0,j2; B j0,j1} (4) ----
  stA(0, 0); stA(0, 1); stA(0, 2); stA(0, 3); stB(0, 0); stB(0, 1);
  stA(1, 0); stA(1, 2); stB(1, 0); stB(1, 1);
  VMCNT(4);                                  // tile 0's 6 loads landed
  SBAR();

  #pragma unroll
  for (int t = 0; t < 16; ++t) {             // K = 16 tiles x BK=32
    // -- q0: m-frags 0,1 --
    if (t < 15) { stA(t + 1, 1); stA(t + 1, 3); }   // pending buffer
    ldA(alo, t, 0);
    ldB(t);
    SBAR(); LGKM0();
    mmah(alo, 0);
    SBAR();
    // -- q1: m-frags 2,3 --
    if (t < 14) { stA(t + 2, 0); stA(t + 2, 2); stB(t + 2, 0); stB(t + 2, 1); }
    ldA(ahi, t, 1);
    if (t < 14) { VMCNT(4); }                // tile t+1 fully resident
    else if (t == 14) { VMCNT(0); }          // tail drain for tile 15
    SBAR(); LGKM0();
    mmah(ahi, 1);
    SBAR();
  }

  __syncthreads();  // all frag reads done; LDS reusable for epilogue

  // ---- fused epilogue: C-layout n=col, d=reg&3, tree-in-frag=2g+hi ----
  float* eb = (float*)smem;                  // [128 batch][68] floats
  const float inv_tau = 1.0f / TAU;
  const int t0 = m0 >> 2;                    // 64 trees per block
  #pragma unroll
  for (int af = 0; af < 4; ++af) {
    #pragma unroll
    for (int g = 0; g < 4; ++g) {
      int tl = wm * 32 + af * 8 + 2 * g + hi;
      int tg = t0 + tl;
      float4 th  = *(const float4*)(thr + tg * 4);
      float4 lf0 = *(const float4*)(leaf + tg * 16);
      float4 lf1 = *(const float4*)(leaf + tg * 16 + 4);
      float4 lf2 = *(const float4*)(leaf + tg * 16 + 8);
      float4 lf3 = *(const float4*)(leaf + tg * 16 + 12);
      float c2x = th.x * inv_tau, c2y = th.y * inv_tau,
            c2z = th.z * inv_tau, c2w = th.w * inv_tau;
      #pragma unroll
      for (int nf = 0; nf < 2; ++nf) {
        float p0 = __builtin_amdgcn_rcpf(1.0f + __expf(fmaf(acc[af][nf][g * 4 + 0], -inv_tau, c2x)));
        float p1 = __builtin_amdgcn_rcpf(1.0f + __expf(fmaf(acc[af][nf][g * 4 + 1], -inv_tau, c2y)));
        float p2 = __builtin_amdgcn_rcpf(1.0f + __expf(fmaf(acc[af][nf][g * 4 + 2], -inv_tau, c2z)));
        float p3 = __builtin_amdgcn_rcpf(1.0f + __expf(fmaf(acc[af][nf][g * 4 + 3], -inv_tau, c2w)));
        float q0 = 1.0f - p0, q1 = 1.0f - p1, q2 = 1.0f - p2, q3 = 1.0f - p3;
        float A0 = lf0.x * q0 + lf0.y * p0;
        float A1 = lf0.z * q0 + lf0.w * p0;
        float A2 = lf1.x * q0 + lf1.y * p0;
        float A3 = lf1.z * q0 + lf1.w * p0;
        float A4 = lf2.x * q0 + lf2.y * p0;
        float A5 = lf2.z * q0 + lf2.w * p0;
        float A6 = lf3.x * q0 + lf3.y * p0;
        float A7 = lf3.z * q0 + lf3.w * p0;
        float B0 = A0 * q1 + A1 * p1;
        float B1 = A2 * q1 + A3 * p1;
        float B2 = A4 * q1 + A5 * p1;
        float B3 = A6 * q1 + A7 * p1;
        float C0 = B0 * q2 + B1 * p2;
        float C1 = B2 * q2 + B3 * p2;
        float o  = C0 * q3 + C1 * p3;
        int bl = wn * 64 + nf * 32 + col;    // batch within block [0,128)
        eb[bl * 68 + tl] = o;
      }
    }
  }
  __syncthreads();

  // coalesced store: 128 batch rows x 64 trees, float4 per thread-slot
  #pragma unroll
  for (int pass = 0; pass < 8; ++pass) {
    int row = pass * 16 + (tid >> 4);
    int s   = tid & 15;
    float4 v = *(const float4*)(eb + row * 68 + s * 4);
    *(float4*)(out + (size_t)(n0 + row) * T_ + t0 + s * 4) = v;
  }
}

extern "C" void kernel_launch(void* const* d_in, const int* in_sizes, int n_in,
                              void* d_out, int out_size, void* d_ws, size_t ws_size,
                              hipStream_t stream) {
  const float* x    = (const float*)d_in[0];  // (B, F)
  const float* fl   = (const float*)d_in[1];  // (T, D, F)
  const float* thr  = (const float*)d_in[2];  // (T, D)
  const float* leaf = (const float*)d_in[3];  // (T, 16)
  float* out = (float*)d_out;                 // (B, T)

  unsigned short* wbF = (unsigned short*)d_ws;                                  // 8 MB
  unsigned short* xbF = (unsigned short*)((char*)d_ws + (size_t)KC_ * M_ * 16); // 4 MB

  prep<<<dim3(1024 + M_ / 4), dim3(256), 0, stream>>>(x, fl, xbF, wbF);
  odst_mfma<<<dim3(M_ / 256, B_ / 128), dim3(256), 0, stream>>>(wbF, xbF, thr, leaf, out);
}